// Round 1
// baseline (138.076 us; speedup 1.0000x reference)
//
#include <hip/hip_runtime.h>

#define BB   16
#define NN   512
#define DIN  256
#define COUT 32
#define CCS  48
#define HH   256
#define WWG  256
#define HW   (HH * WWG)
#define CTOT (CCS + COUT)

// ---------------------------------------------------------------------------
// winner[b*HW + h*W + w] = max n among entities landing on that cell, else -1
// ---------------------------------------------------------------------------
__global__ void k_init_winner(int* __restrict__ winner) {
    int i = blockIdx.x * blockDim.x + threadIdx.x;
    if (i < BB * HW) winner[i] = -1;
}

__global__ void k_winner(const int* __restrict__ loc, int* __restrict__ winner) {
    int i = blockIdx.x * blockDim.x + threadIdx.x;   // i = b*NN + n
    if (i >= BB * NN) return;
    int b = i / NN;
    int n = i - b * NN;
    int h = loc[2 * i + 0];
    int w = loc[2 * i + 1];
    atomicMax(&winner[b * HW + h * WWG + w], n);
}

// ---------------------------------------------------------------------------
// proj[b,n,c] = sum_d emb[b,n,d] * W[d,c] + bias[c]
// W (256x32 f32 = 32KB) staged in LDS; 8 entity-rows per 256-thread block.
// ---------------------------------------------------------------------------
__global__ void k_proj(const float* __restrict__ emb, const float* __restrict__ Wm,
                       const float* __restrict__ bias, float* __restrict__ proj) {
    __shared__ float Wl[DIN * COUT];
    int tid = threadIdx.x;
    for (int i = tid; i < DIN * COUT; i += blockDim.x) Wl[i] = Wm[i];
    __syncthreads();
    int c = tid & 31;
    int r = tid >> 5;                       // 0..7
    int row = blockIdx.x * 8 + r;           // entity index in [0, B*N)
    if (row >= BB * NN) return;
    const float* e = emb + (size_t)row * DIN;
    float acc = bias[c];
    #pragma unroll 8
    for (int d = 0; d < DIN; ++d)
        acc += e[d] * Wl[d * COUT + c];     // e[d] wave-uniform broadcast; Wl conflict-free
    proj[(size_t)row * COUT + c] = acc;
}

// ---------------------------------------------------------------------------
// out[b, ch, pix]: ch < 48 -> copy spatial; ch >= 48 -> zero. float4 per thread.
// ---------------------------------------------------------------------------
__global__ void k_fill(const float* __restrict__ sp, float* __restrict__ out) {
    long long i4 = (long long)blockIdx.x * blockDim.x + threadIdx.x;
    const long long TOT4 = (long long)BB * CTOT * HW / 4;
    if (i4 >= TOT4) return;
    long long i = i4 * 4;
    int pix = (int)(i % HW);                // HW divisible by 4 -> float4 stays in-channel
    long long t = i / HW;
    int ch = (int)(t % CTOT);
    int b  = (int)(t / CTOT);
    float4 v;
    if (ch < CCS) {
        v = *(const float4*)(sp + ((size_t)(b * CCS + ch) * HW + pix));
    } else {
        v = make_float4(0.f, 0.f, 0.f, 0.f);
    }
    *(float4*)(out + i) = v;
}

// ---------------------------------------------------------------------------
// winning entity writes its 32-channel proj vector to out[b, 48+c, h, w]
// 32 threads per entity (one per channel).
// ---------------------------------------------------------------------------
__global__ void k_scatter(const float* __restrict__ proj, const int* __restrict__ loc,
                          const int* __restrict__ winner, float* __restrict__ out) {
    int t = blockIdx.x * blockDim.x + threadIdx.x;
    if (t >= BB * NN * COUT) return;
    int c = t & 31;
    int i = t >> 5;                          // b*NN + n
    int b = i / NN;
    int n = i - b * NN;
    int h = loc[2 * i + 0];
    int w = loc[2 * i + 1];
    int cell = b * HW + h * WWG + w;
    if (winner[cell] != n) return;           // last-write-wins (max n)
    out[((size_t)b * CTOT + CCS + c) * HW + (size_t)h * WWG + w] =
        proj[(size_t)i * COUT + c];
}

extern "C" void kernel_launch(void* const* d_in, const int* in_sizes, int n_in,
                              void* d_out, int out_size, void* d_ws, size_t ws_size,
                              hipStream_t stream) {
    const float* sp   = (const float*)d_in[0];   // [16,48,256,256]
    const float* emb  = (const float*)d_in[1];   // [16,512,256]
    const float* Wm   = (const float*)d_in[2];   // [256,32]
    const float* bias = (const float*)d_in[3];   // [32]
    const int*   loc  = (const int*)d_in[4];     // [16,512,2]
    float* out = (float*)d_out;                  // [16,80,256,256]

    float* proj  = (float*)d_ws;                                   // 1 MB
    int* winner  = (int*)((char*)d_ws + (size_t)BB * NN * COUT * 4); // 4 MB

    hipLaunchKernelGGL(k_init_winner, dim3((BB * HW + 255) / 256), dim3(256), 0, stream,
                       winner);
    hipLaunchKernelGGL(k_proj, dim3(BB * NN / 8), dim3(256), 0, stream,
                       emb, Wm, bias, proj);
    hipLaunchKernelGGL(k_winner, dim3((BB * NN + 255) / 256), dim3(256), 0, stream,
                       loc, winner);
    const long long TOT4 = (long long)BB * CTOT * HW / 4;          // 20,971,520
    hipLaunchKernelGGL(k_fill, dim3((unsigned)((TOT4 + 255) / 256)), dim3(256), 0, stream,
                       sp, out);
    hipLaunchKernelGGL(k_scatter, dim3(BB * NN * COUT / 256), dim3(256), 0, stream,
                       proj, loc, winner, out);
}

// Round 2
// 116.608 us; speedup vs baseline: 1.1841x; 1.1841x over previous
//
#include <hip/hip_runtime.h>

typedef float f4 __attribute__((ext_vector_type(4)));

#define BB   16
#define NN   512
#define DIN  256
#define COUT 32
#define CCS  48
#define HH   256
#define WWG  256
#define HW   (HH * WWG)          // 65536 = 1<<16
#define CTOT (CCS + COUT)        // 80

// ---------------------------------------------------------------------------
// Fused: blocks [0,1024) compute proj = emb·W + b  (8 entity-rows per block,
// W staged in LDS); blocks [1024,1056) do the winner atomicMax scatter-resolve.
// winner[] must be pre-set to -1 (async memset of 0xFF) before this kernel.
// ---------------------------------------------------------------------------
__global__ __launch_bounds__(256) void k_projwin(
        const float* __restrict__ emb, const float* __restrict__ Wm,
        const float* __restrict__ bias, const int* __restrict__ loc,
        float* __restrict__ proj, int* __restrict__ winner) {
    __shared__ float Wl[DIN * COUT];
    int tid = threadIdx.x;
    if (blockIdx.x < 1024) {
        for (int i = tid; i < DIN * COUT; i += 256) Wl[i] = Wm[i];
        __syncthreads();
        int c = tid & 31;
        int r = tid >> 5;                        // 0..7
        int row = blockIdx.x * 8 + r;            // entity index in [0, 8192)
        const float* e = emb + (size_t)row * DIN;
        float acc = bias[c];
        #pragma unroll 8
        for (int d = 0; d < DIN; ++d)
            acc += e[d] * Wl[d * COUT + c];      // e[d] uniform broadcast; Wl conflict-free
        proj[(size_t)row * COUT + c] = acc;
    } else {
        int i = (blockIdx.x - 1024) * 256 + tid; // 0..8191 = b*NN + n
        int b = i >> 9;
        int n = i & (NN - 1);
        int h = loc[2 * i + 0];
        int w = loc[2 * i + 1];
        atomicMax(&winner[b * HW + h * WWG + w], n);  // last-write-wins = max n
    }
}

// ---------------------------------------------------------------------------
// out[b, ch, pix]: ch < 48 -> copy spatial; ch >= 48 -> zero.
// 3D grid (x: 64 pix-blocks, y: 80 channels, z: 16 batches); one float4/thread;
// no per-thread div/mod; nontemporal (streaming, zero reuse).
// ---------------------------------------------------------------------------
__global__ __launch_bounds__(256) void k_fill(const float* __restrict__ sp,
                                              float* __restrict__ out) {
    int pix4 = blockIdx.x * 256 + threadIdx.x;   // float4 index within channel, 0..16383
    int ch = blockIdx.y;
    int b  = blockIdx.z;
    f4 v = (f4)(0.0f);
    if (ch < CCS) {
        const f4* s = (const f4*)sp + (((size_t)(b * CCS + ch) << 14) + pix4);
        v = __builtin_nontemporal_load(s);
    }
    f4* o = (f4*)out + (((size_t)(b * CTOT + ch) << 14) + pix4);
    __builtin_nontemporal_store(v, o);
}

// ---------------------------------------------------------------------------
// Winning entity writes its 32-channel proj vector to out[b, 48+c, h, w].
// 32 threads per entity (one per channel).
// ---------------------------------------------------------------------------
__global__ __launch_bounds__(256) void k_scatter(
        const float* __restrict__ proj, const int* __restrict__ loc,
        const int* __restrict__ winner, float* __restrict__ out) {
    int t = blockIdx.x * 256 + threadIdx.x;
    int c = t & 31;
    int i = t >> 5;                              // b*NN + n
    int b = i >> 9;
    int n = i & (NN - 1);
    int h = loc[2 * i + 0];
    int w = loc[2 * i + 1];
    int cell = b * HW + h * WWG + w;
    if (winner[cell] != n) return;
    out[((size_t)(b * CTOT + CCS + c) << 16) + (size_t)h * WWG + w] =
        proj[(size_t)i * COUT + c];
}

extern "C" void kernel_launch(void* const* d_in, const int* in_sizes, int n_in,
                              void* d_out, int out_size, void* d_ws, size_t ws_size,
                              hipStream_t stream) {
    const float* sp   = (const float*)d_in[0];   // [16,48,256,256]
    const float* emb  = (const float*)d_in[1];   // [16,512,256]
    const float* Wm   = (const float*)d_in[2];   // [256,32]
    const float* bias = (const float*)d_in[3];   // [32]
    const int*   loc  = (const int*)d_in[4];     // [16,512,2] (int64 in ref -> int32 here per harness)
    float* out = (float*)d_out;                  // [16,80,256,256]

    float* proj  = (float*)d_ws;                                     // 1 MB
    int*   winner = (int*)((char*)d_ws + (size_t)BB * NN * COUT * 4); // 4 MB

    // winner = -1 everywhere (0xFF bytes)
    hipMemsetAsync(winner, 0xFF, (size_t)BB * HW * sizeof(int), stream);

    hipLaunchKernelGGL(k_projwin, dim3(1024 + BB * NN / 256), dim3(256), 0, stream,
                       emb, Wm, bias, loc, proj, winner);

    hipLaunchKernelGGL(k_fill, dim3(HW / 4 / 256, CTOT, BB), dim3(256), 0, stream,
                       sp, out);

    hipLaunchKernelGGL(k_scatter, dim3(BB * NN * COUT / 256), dim3(256), 0, stream,
                       proj, loc, winner, out);
}